// Round 1
// baseline (255.611 us; speedup 1.0000x reference)
//
#include <hip/hip_runtime.h>
#include <math.h>

#define NPROP 2048
#define NCLS 81
#define GCAP 8192

// ws layout:
//   probs : float[2048*81]            @ 0        (663552 B)
//   gcount: int                       @ 663552
//   glist : ull[GCAP]                 @ 663560   (65536 B)
// total ~729 KB

__device__ __forceinline__ void decode_clip(const float* __restrict__ props,
                                            const float* __restrict__ reg,
                                            int p, int cls, float out[4]) {
    float px1 = props[p * 4 + 0], py1 = props[p * 4 + 1];
    float px2 = props[p * 4 + 2], py2 = props[p * 4 + 3];
    float w = px2 - px1 + 1.0f;
    float h = py2 - py1 + 1.0f;
    float cx = px1 + 0.5f * w;
    float cy = py1 + 0.5f * h;
    const float* r = reg + (size_t)p * (NCLS * 4) + cls * 4;
    float dx = r[0] / 10.0f;
    float dy = r[1] / 10.0f;
    float dw = fminf(r[2] / 5.0f, 4.135166556742356f);
    float dh = fminf(r[3] / 5.0f, 4.135166556742356f);
    float pcx = dx * w + cx;
    float pcy = dy * h + cy;
    float pw = expf(dw) * w;
    float ph = expf(dh) * h;
    float x1 = pcx - 0.5f * pw;
    float y1 = pcy - 0.5f * ph;
    float x2 = pcx + 0.5f * pw - 1.0f;
    float y2 = pcy + 0.5f * ph - 1.0f;
    out[0] = fminf(fmaxf(x1, 0.0f), 1332.0f);
    out[1] = fminf(fmaxf(y1, 0.0f), 799.0f);
    out[2] = fminf(fmaxf(x2, 0.0f), 1332.0f);
    out[3] = fminf(fmaxf(y2, 0.0f), 799.0f);
}

// one wave (64 lanes) per proposal row
__global__ __launch_bounds__(256) void softmax_kernel(const float* __restrict__ logits,
                                                      float* __restrict__ probs,
                                                      int* __restrict__ gcount) {
    if (blockIdx.x == 0 && threadIdx.x == 0) *gcount = 0;
    int gw = (blockIdx.x * blockDim.x + threadIdx.x) >> 6;
    int lane = threadIdx.x & 63;
    if (gw >= NPROP) return;
    const float* row = logits + (size_t)gw * NCLS;
    float a = row[lane];                                    // lane < 64 < 81
    bool hasb = (lane + 64) < NCLS;
    float b = hasb ? row[lane + 64] : -INFINITY;
    float m = fmaxf(a, b);
    #pragma unroll
    for (int s = 32; s; s >>= 1) m = fmaxf(m, __shfl_xor(m, s));
    float ea = expf(a - m);
    float eb = hasb ? expf(b - m) : 0.0f;
    float sum = ea + eb;
    #pragma unroll
    for (int s = 32; s; s >>= 1) sum += __shfl_xor(sum, s);
    float* prow = probs + (size_t)gw * NCLS;
    prow[lane] = ea / sum;
    if (hasb) prow[lane + 64] = eb / sum;
}

// one block per foreground class (blockIdx.x = class-1 in [0,80))
__global__ __launch_bounds__(256) void nms_kernel(const float* __restrict__ probs,
                                                  const float* __restrict__ props,
                                                  const float* __restrict__ reg,
                                                  int* __restrict__ gcount,
                                                  unsigned long long* __restrict__ glist) {
    const int c = blockIdx.x;      // class index minus 1
    const int tid = threadIdx.x;
    __shared__ unsigned long long keys[NPROP];
    __shared__ float4 bx[NPROP];
    __shared__ unsigned int sup[NPROP / 32];
    __shared__ int cnt;
    if (tid == 0) cnt = 0;
    for (int i = tid; i < NPROP; i += 256) keys[i] = 0ULL;
    for (int i = tid; i < NPROP / 32; i += 256) sup[i] = 0u;
    __syncthreads();

    // gather valid (score > 0.05)
    for (int p = tid; p < NPROP; p += 256) {
        float s = probs[(size_t)p * NCLS + c + 1];
        if (s > 0.05f) {
            int idx = atomicAdd(&cnt, 1);
            keys[idx] = ((unsigned long long)__float_as_uint(s) << 32) |
                        (unsigned int)(~p);
        }
    }
    __syncthreads();
    const int M = cnt;

    // bitonic sort descending (zeros sink to the back)
    for (int k = 2; k <= NPROP; k <<= 1) {
        for (int j = k >> 1; j > 0; j >>= 1) {
            for (int i = tid; i < NPROP; i += 256) {
                int l = i ^ j;
                if (l > i) {
                    unsigned long long a = keys[i], b = keys[l];
                    bool dir = ((i & k) == 0);
                    if ((a < b) == dir) { keys[i] = b; keys[l] = a; }
                }
            }
            __syncthreads();
        }
    }

    // decode boxes for valid entries (in sorted order)
    for (int i = tid; i < M; i += 256) {
        int p = (int)(~(unsigned int)keys[i]);
        float b4[4];
        decode_clip(props, reg, p, c + 1, b4);
        bx[i] = make_float4(b4[0], b4[1], b4[2], b4[3]);
    }
    __syncthreads();

    // greedy NMS: sequential over i, parallel over j
    for (int i = 0; i < M; ++i) {
        __syncthreads();
        if ((sup[i >> 5] >> (i & 31)) & 1u) continue;
        float4 bi = bx[i];
        float ai = (bi.z - bi.x + 1.0f) * (bi.w - bi.y + 1.0f);
        for (int j = i + 1 + tid; j < M; j += 256) {
            float4 bj = bx[j];
            float aj = (bj.z - bj.x + 1.0f) * (bj.w - bj.y + 1.0f);
            float ltx = fmaxf(bi.x, bj.x), lty = fmaxf(bi.y, bj.y);
            float rbx = fminf(bi.z, bj.z), rby = fminf(bi.w, bj.w);
            float iw = fmaxf(rbx - ltx + 1.0f, 0.0f);
            float ih = fmaxf(rby - lty + 1.0f, 0.0f);
            float inter = iw * ih;
            float iou = inter / (ai + aj - inter);
            if (iou > 0.5f) atomicOr(&sup[j >> 5], 1u << (j & 31));
        }
    }
    __syncthreads();

    // push survivors to global list, re-keyed by flat index for global top-k
    for (int i = tid; i < M; i += 256) {
        if (!((sup[i >> 5] >> (i & 31)) & 1u)) {
            unsigned long long key = keys[i];
            int p = (int)(~(unsigned int)key);
            int flat = c * NPROP + p;
            int pos = atomicAdd(gcount, 1);
            if (pos < GCAP)
                glist[pos] = (key & 0xFFFFFFFF00000000ULL) | (unsigned int)(~flat);
        }
    }
}

// single block: sort all survivors, emit top-100
__global__ __launch_bounds__(1024) void topk_kernel(const int* __restrict__ gcount,
                                                    const unsigned long long* __restrict__ glist,
                                                    const float* __restrict__ props,
                                                    const float* __restrict__ reg,
                                                    float* __restrict__ out) {
    __shared__ unsigned long long sk[GCAP];
    int K = *gcount;
    if (K > GCAP) K = GCAP;
    int tid = threadIdx.x;
    for (int i = tid; i < GCAP; i += 1024) sk[i] = (i < K) ? glist[i] : 0ULL;
    __syncthreads();
    for (int k = 2; k <= GCAP; k <<= 1) {
        for (int j = k >> 1; j > 0; j >>= 1) {
            for (int i = tid; i < GCAP; i += 1024) {
                int l = i ^ j;
                if (l > i) {
                    unsigned long long a = sk[i], b = sk[l];
                    bool dir = ((i & k) == 0);
                    if ((a < b) == dir) { sk[i] = b; sk[l] = a; }
                }
            }
            __syncthreads();
        }
    }
    if (tid < 100) {
        unsigned long long key = sk[tid];
        float score;
        int flat;
        if (key == 0ULL) {          // fewer than 100 survivors (not expected)
            score = -1.0f;
            flat = tid;
        } else {
            score = __uint_as_float((unsigned int)(key >> 32));
            flat = (int)(~(unsigned int)key);
        }
        int cc = flat >> 11;        // NPROP = 2048 = 2^11
        int p = flat & (NPROP - 1);
        float b4[4];
        decode_clip(props, reg, p, cc + 1, b4);
        out[tid * 4 + 0] = b4[0];
        out[tid * 4 + 1] = b4[1];
        out[tid * 4 + 2] = b4[2];
        out[tid * 4 + 3] = b4[3];
        out[400 + tid] = score;
        out[500 + tid] = (float)(cc + 1);
    }
}

extern "C" void kernel_launch(void* const* d_in, const int* in_sizes, int n_in,
                              void* d_out, int out_size, void* d_ws, size_t ws_size,
                              hipStream_t stream) {
    const float* logits = (const float*)d_in[0];
    const float* reg    = (const float*)d_in[1];
    const float* props  = (const float*)d_in[2];
    float* out = (float*)d_out;

    float* probs = (float*)d_ws;
    int* gcount = (int*)((char*)d_ws + 663552);
    unsigned long long* glist = (unsigned long long*)((char*)d_ws + 663560);

    hipLaunchKernelGGL(softmax_kernel, dim3((NPROP * 64) / 256), dim3(256), 0, stream,
                       logits, probs, gcount);
    hipLaunchKernelGGL(nms_kernel, dim3(NCLS - 1), dim3(256), 0, stream,
                       probs, props, reg, gcount, glist);
    hipLaunchKernelGGL(topk_kernel, dim3(1), dim3(1024), 0, stream,
                       gcount, glist, props, reg, out);
}

// Round 4
// 156.406 us; speedup vs baseline: 1.6343x; 1.6343x over previous
//
#include <hip/hip_runtime.h>
#include <math.h>

#define NPROP 2048
#define NCLS 81
#define NFG 80
#define CAP 512        // per-class candidate cap (mean ~59, huge margin)
#define TOPC 100       // per-class survivors that can matter for global top-100

// ws layout:
//   ccnt : int[80]           @ 0       (zeroed via memsetAsync)
//   scnt : int[80]           @ 320     (zeroed via memsetAsync)
//   cand : ull[80*CAP]       @ 640
//   surv : ull[80*CAP]       @ 328320
// total 656000 B

__device__ __forceinline__ void decode_clip(const float* __restrict__ props,
                                            const float* __restrict__ reg,
                                            int p, int cls, float out[4]) {
    float px1 = props[p * 4 + 0], py1 = props[p * 4 + 1];
    float px2 = props[p * 4 + 2], py2 = props[p * 4 + 3];
    float w = px2 - px1 + 1.0f;
    float h = py2 - py1 + 1.0f;
    float cx = px1 + 0.5f * w;
    float cy = py1 + 0.5f * h;
    const float* r = reg + (size_t)p * (NCLS * 4) + cls * 4;
    float dx = r[0] / 10.0f;
    float dy = r[1] / 10.0f;
    float dw = fminf(r[2] / 5.0f, 4.135166556742356f);
    float dh = fminf(r[3] / 5.0f, 4.135166556742356f);
    float pcx = dx * w + cx;
    float pcy = dy * h + cy;
    float pw = expf(dw) * w;
    float ph = expf(dh) * h;
    float x1 = pcx - 0.5f * pw;
    float y1 = pcy - 0.5f * ph;
    float x2 = pcx + 0.5f * pw - 1.0f;
    float y2 = pcy + 0.5f * ph - 1.0f;
    out[0] = fminf(fmaxf(x1, 0.0f), 1332.0f);
    out[1] = fminf(fmaxf(y1, 0.0f), 799.0f);
    out[2] = fminf(fmaxf(x2, 0.0f), 1332.0f);
    out[3] = fminf(fmaxf(y2, 0.0f), 799.0f);
}

// one wave per proposal row: softmax in registers, scatter valid (score>0.05)
// candidates straight into per-class segments.
__global__ __launch_bounds__(256) void softmax_scatter(const float* __restrict__ logits,
                                                       int* __restrict__ ccnt,
                                                       unsigned long long* __restrict__ cand) {
    int gw = (blockIdx.x * blockDim.x + threadIdx.x) >> 6;
    int lane = threadIdx.x & 63;
    if (gw >= NPROP) return;
    const float* row = logits + (size_t)gw * NCLS;
    float a = row[lane];                       // lane < 64 < 81
    bool hasb = (lane + 64) < NCLS;            // lanes 0..16
    float b = hasb ? row[lane + 64] : -INFINITY;
    float m = fmaxf(a, b);
    #pragma unroll
    for (int s = 32; s; s >>= 1) m = fmaxf(m, __shfl_xor(m, s));
    float ea = expf(a - m);
    float eb = hasb ? expf(b - m) : 0.0f;
    float sum = ea + eb;
    #pragma unroll
    for (int s = 32; s; s >>= 1) sum += __shfl_xor(sum, s);
    float pa = ea / sum;
    float pb = eb / sum;
    unsigned int np = (unsigned int)(~gw);
    if (lane != 0 && pa > 0.05f) {             // skip background class 0
        int c = lane - 1;
        int pos = atomicAdd(&ccnt[c], 1);
        if (pos < CAP)
            cand[c * CAP + pos] =
                ((unsigned long long)__float_as_uint(pa) << 32) | np;
    }
    if (hasb && pb > 0.05f) {                  // classes 64..80 -> c = 63..79
        int c = lane + 63;
        int pos = atomicAdd(&ccnt[c], 1);
        if (pos < CAP)
            cand[c * CAP + pos] =
                ((unsigned long long)__float_as_uint(pb) << 32) | np;
    }
}

// one block per foreground class: sort the M valid candidates (M ~ 59),
// greedy NMS, emit survivors (descending score) re-keyed with ~flat.
__global__ __launch_bounds__(256) void nms_kernel(const int* __restrict__ ccnt,
                                                  const unsigned long long* __restrict__ cand,
                                                  const float* __restrict__ props,
                                                  const float* __restrict__ reg,
                                                  int* __restrict__ scnt,
                                                  unsigned long long* __restrict__ surv) {
    const int c = blockIdx.x;
    const int tid = threadIdx.x;
    __shared__ unsigned long long keys[CAP];
    __shared__ float4 bx[CAP];
    __shared__ unsigned int sup[CAP / 32];
    int M = ccnt[c];
    if (M > CAP) M = CAP;
    if (M == 0) { if (tid == 0) scnt[c] = 0; return; }
    int S = 1;
    while (S < M) S <<= 1;

    for (int i = tid; i < S; i += 256)
        keys[i] = (i < M) ? cand[c * CAP + i] : 0ULL;
    for (int i = tid; i < CAP / 32; i += 256) sup[i] = 0u;
    __syncthreads();

    // bitonic sort descending over S (pow2) elements; zero pads sink to back
    for (int k = 2; k <= S; k <<= 1) {
        for (int j = k >> 1; j > 0; j >>= 1) {
            for (int i = tid; i < S; i += 256) {
                int l = i ^ j;
                if (l > i) {
                    unsigned long long A = keys[i], B = keys[l];
                    bool dir = ((i & k) == 0);
                    if ((A < B) == dir) { keys[i] = B; keys[l] = A; }
                }
            }
            __syncthreads();
        }
    }

    // decode clipped boxes for the M sorted candidates
    for (int i = tid; i < M; i += 256) {
        int p = (int)(~(unsigned int)keys[i]);
        float b4[4];
        decode_clip(props, reg, p, c + 1, b4);
        bx[i] = make_float4(b4[0], b4[1], b4[2], b4[3]);
    }
    __syncthreads();

    // greedy NMS: sequential i, parallel j
    for (int i = 0; i < M; ++i) {
        __syncthreads();
        if ((sup[i >> 5] >> (i & 31)) & 1u) continue;
        float4 bi = bx[i];
        float ai = (bi.z - bi.x + 1.0f) * (bi.w - bi.y + 1.0f);
        for (int j = i + 1 + tid; j < M; j += 256) {
            float4 bj = bx[j];
            float aj = (bj.z - bj.x + 1.0f) * (bj.w - bj.y + 1.0f);
            float ltx = fmaxf(bi.x, bj.x), lty = fmaxf(bi.y, bj.y);
            float rbx = fminf(bi.z, bj.z), rby = fminf(bi.w, bj.w);
            float iw = fmaxf(rbx - ltx + 1.0f, 0.0f);
            float ih = fmaxf(rby - lty + 1.0f, 0.0f);
            float inter = iw * ih;
            float iou = inter / (ai + aj - inter);
            if (iou > 0.5f) atomicOr(&sup[j >> 5], 1u << (j & 31));
        }
    }
    __syncthreads();

    // wave 0 ballot-compacts survivors (keeps descending order),
    // re-keying with ~flat so topk can recover (class, prop) and tie-break.
    if (tid < 64) {
        int lane = tid;
        int base = 0;
        for (int j0 = 0; j0 < M; j0 += 64) {
            int idx = j0 + lane;
            bool keep = (idx < M) && !((sup[idx >> 5] >> (idx & 31)) & 1u);
            unsigned long long mask = __ballot(keep);
            if (keep) {
                int pos = base + __popcll(mask & ((1ULL << lane) - 1ULL));
                unsigned long long key = keys[idx];
                int p = (int)(~(unsigned int)key);
                unsigned int flat = (unsigned int)(c * NPROP + p);
                surv[c * CAP + pos] =
                    (key & 0xFFFFFFFF00000000ULL) | (unsigned int)(~flat);
            }
            base += __popcll(mask);
        }
        if (lane == 0) scnt[c] = base;
    }
}

// single block: 100-step 80-way merge of the per-class sorted survivor lists.
__global__ __launch_bounds__(256) void topk_kernel(const int* __restrict__ scnt,
                                                   const unsigned long long* __restrict__ surv,
                                                   const float* __restrict__ props,
                                                   const float* __restrict__ reg,
                                                   float* __restrict__ out) {
    __shared__ int s_cnt[NFG];
    __shared__ unsigned long long seg[NFG * TOPC];   // 64000 B
    __shared__ unsigned long long winners[TOPC];
    const int tid = threadIdx.x;

    for (int i = tid; i < NFG; i += 256) {
        int k = scnt[i];
        s_cnt[i] = (k > TOPC) ? TOPC : k;
    }
    __syncthreads();
    for (int idx = tid; idx < NFG * TOPC; idx += 256) {
        int cc = idx / TOPC;
        int i = idx - cc * TOPC;
        seg[idx] = (i < s_cnt[cc]) ? surv[cc * CAP + i] : 0ULL;
    }
    __syncthreads();

    if (tid < 64) {
        int lane = tid;
        int c1 = lane;                 // classes 0..63
        int c2 = 64 + lane;            // classes 64..79 (lanes 0..15)
        bool has2 = lane < (NFG - 64);
        int n1 = s_cnt[c1];
        int n2 = has2 ? s_cnt[c2] : 0;
        int h1 = 0, h2 = 0;
        for (int it = 0; it < TOPC; ++it) {
            unsigned long long k1 = (h1 < n1) ? seg[c1 * TOPC + h1] : 0ULL;
            unsigned long long k2 = (h2 < n2) ? seg[c2 * TOPC + h2] : 0ULL;
            unsigned long long km = (k1 > k2) ? k1 : k2;
            #pragma unroll
            for (int s = 32; s; s >>= 1) {
                unsigned long long o = __shfl_xor(km, s);
                km = (o > km) ? o : km;
            }
            if (lane == 0) winners[it] = km;
            if (km != 0ULL) {
                unsigned int flat = ~(unsigned int)km;
                int wc = (int)(flat >> 11);          // NPROP = 2^11
                if (wc == c1 && k1 == km) h1++;
                else if (has2 && wc == c2 && k2 == km) h2++;
            }
        }
    }
    __syncthreads();

    if (tid < TOPC) {
        unsigned long long key = winners[tid];
        float score;
        int flat;
        if (key == 0ULL) {             // < 100 total survivors: unreachable here
            score = -1.0f;
            flat = tid;
        } else {
            score = __uint_as_float((unsigned int)(key >> 32));
            flat = (int)(~(unsigned int)key);
        }
        int cc = flat >> 11;
        int p = flat & (NPROP - 1);
        float b4[4];
        decode_clip(props, reg, p, cc + 1, b4);
        out[tid * 4 + 0] = b4[0];
        out[tid * 4 + 1] = b4[1];
        out[tid * 4 + 2] = b4[2];
        out[tid * 4 + 3] = b4[3];
        out[400 + tid] = score;
        out[500 + tid] = (float)(cc + 1);
    }
}

extern "C" void kernel_launch(void* const* d_in, const int* in_sizes, int n_in,
                              void* d_out, int out_size, void* d_ws, size_t ws_size,
                              hipStream_t stream) {
    const float* logits = (const float*)d_in[0];
    const float* reg    = (const float*)d_in[1];
    const float* props  = (const float*)d_in[2];
    float* out = (float*)d_out;

    int* ccnt = (int*)d_ws;
    int* scnt = (int*)((char*)d_ws + 320);
    unsigned long long* cand = (unsigned long long*)((char*)d_ws + 640);
    unsigned long long* surv = (unsigned long long*)((char*)d_ws + 328320);

    hipMemsetAsync(d_ws, 0, 640, stream);
    hipLaunchKernelGGL(softmax_scatter, dim3((NPROP * 64) / 256), dim3(256), 0, stream,
                       logits, ccnt, cand);
    hipLaunchKernelGGL(nms_kernel, dim3(NFG), dim3(256), 0, stream,
                       ccnt, cand, props, reg, scnt, surv);
    hipLaunchKernelGGL(topk_kernel, dim3(1), dim3(256), 0, stream,
                       scnt, surv, props, reg, out);
}

// Round 5
// 131.739 us; speedup vs baseline: 1.9403x; 1.1872x over previous
//
#include <hip/hip_runtime.h>
#include <math.h>

#define NPROP 2048
#define NCLS 81
#define NFG 80
#define CAP 512        // per-class candidate cap (mean ~59, huge margin)
#define TOPC 100       // per-class survivors that can matter for global top-100
#define CPAD 16        // ints per counter (64B cacheline padding)
#define NB 1152        // score histogram buckets
#define BMIN 0x7A99    // (bits(0.05f+) >> 15)

// ws layout:
//   ccnt : int[80*16]   @ 0       (5120 B, zeroed via memsetAsync)
//   scnt : int[80]      @ 5120    (fully written by nms_kernel)
//   cand : ull[80*512]  @ 5440
//   surv : ull[80*512]  @ 333120  (end 660800)

#define LDS_FENCE() do { __builtin_amdgcn_wave_barrier(); \
    asm volatile("s_waitcnt lgkmcnt(0)" ::: "memory");     \
    __builtin_amdgcn_wave_barrier(); } while (0)

__device__ __forceinline__ void decode_clip(const float* __restrict__ props,
                                            const float* __restrict__ reg,
                                            int p, int cls, float out[4]) {
    float px1 = props[p * 4 + 0], py1 = props[p * 4 + 1];
    float px2 = props[p * 4 + 2], py2 = props[p * 4 + 3];
    float w = px2 - px1 + 1.0f;
    float h = py2 - py1 + 1.0f;
    float cx = px1 + 0.5f * w;
    float cy = py1 + 0.5f * h;
    const float* r = reg + (size_t)p * (NCLS * 4) + cls * 4;
    float dx = r[0] / 10.0f;
    float dy = r[1] / 10.0f;
    float dw = fminf(r[2] / 5.0f, 4.135166556742356f);
    float dh = fminf(r[3] / 5.0f, 4.135166556742356f);
    float pcx = dx * w + cx;
    float pcy = dy * h + cy;
    float pw = expf(dw) * w;
    float ph = expf(dh) * h;
    float x1 = pcx - 0.5f * pw;
    float y1 = pcy - 0.5f * ph;
    float x2 = pcx + 0.5f * pw - 1.0f;
    float y2 = pcy + 0.5f * ph - 1.0f;
    out[0] = fminf(fmaxf(x1, 0.0f), 1332.0f);
    out[1] = fminf(fmaxf(y1, 0.0f), 799.0f);
    out[2] = fminf(fmaxf(x2, 0.0f), 1332.0f);
    out[3] = fminf(fmaxf(y2, 0.0f), 799.0f);
}

// one wave per proposal row: softmax in registers, scatter valid (score>0.05)
// candidates into per-class segments (counters padded to one cacheline each).
__global__ __launch_bounds__(256) void softmax_scatter(const float* __restrict__ logits,
                                                       int* __restrict__ ccnt,
                                                       unsigned long long* __restrict__ cand) {
    int gw = (blockIdx.x * blockDim.x + threadIdx.x) >> 6;
    int lane = threadIdx.x & 63;
    if (gw >= NPROP) return;
    const float* row = logits + (size_t)gw * NCLS;
    float a = row[lane];                       // lane < 64 < 81
    bool hasb = (lane + 64) < NCLS;            // lanes 0..16
    float b = hasb ? row[lane + 64] : -INFINITY;
    float m = fmaxf(a, b);
    #pragma unroll
    for (int s = 32; s; s >>= 1) m = fmaxf(m, __shfl_xor(m, s));
    float ea = expf(a - m);
    float eb = hasb ? expf(b - m) : 0.0f;
    float sum = ea + eb;
    #pragma unroll
    for (int s = 32; s; s >>= 1) sum += __shfl_xor(sum, s);
    float pa = ea / sum;
    float pb = eb / sum;
    unsigned int np = (unsigned int)(~gw);
    if (lane != 0 && pa > 0.05f) {             // skip background class 0
        int c = lane - 1;
        int pos = atomicAdd(&ccnt[c * CPAD], 1);
        if (pos < CAP)
            cand[c * CAP + pos] =
                ((unsigned long long)__float_as_uint(pa) << 32) | np;
    }
    if (hasb && pb > 0.05f) {                  // classes 64..80 -> c = 63..79
        int c = lane + 63;
        int pos = atomicAdd(&ccnt[c * CPAD], 1);
        if (pos < CAP)
            cand[c * CAP + pos] =
                ((unsigned long long)__float_as_uint(pb) << 32) | np;
    }
}

// ONE WAVE per foreground class: wave-synchronous sort + register-resident
// greedy NMS (no __syncthreads anywhere).
__global__ __launch_bounds__(64) void nms_kernel(const int* __restrict__ ccnt,
                                                 const unsigned long long* __restrict__ cand,
                                                 const float* __restrict__ props,
                                                 const float* __restrict__ reg,
                                                 int* __restrict__ scnt,
                                                 unsigned long long* __restrict__ surv) {
    const int c = blockIdx.x;
    const int lane = threadIdx.x;
    __shared__ unsigned long long keys[CAP];
    __shared__ float4 bx[CAP];
    int M = ccnt[c * CPAD];
    if (M > CAP) M = CAP;
    if (M == 0) { if (lane == 0) scnt[c] = 0; return; }
    int S = 64;
    while (S < M) S <<= 1;

    for (int i = lane; i < S; i += 64)
        keys[i] = (i < M) ? cand[c * CAP + i] : 0ULL;
    LDS_FENCE();

    // wave-synchronous bitonic sort descending (zero pads sink to back)
    for (int k = 2; k <= S; k <<= 1) {
        for (int j = k >> 1; j > 0; j >>= 1) {
            for (int i = lane; i < S; i += 64) {
                int l = i ^ j;
                if (l > i) {
                    unsigned long long A = keys[i], B = keys[l];
                    bool dir = ((i & k) == 0);
                    if ((A < B) == dir) { keys[i] = B; keys[l] = A; }
                }
            }
            LDS_FENCE();
        }
    }

    // decode boxes: own slots to registers, all to LDS for broadcast
    float4 myb[8];
    #pragma unroll
    for (int ns = 0; ns < 8; ++ns) {
        int idx = lane + ns * 64;
        if (idx < M) {
            unsigned long long key = keys[idx];
            int p = (int)(~(unsigned int)key);
            float b4[4];
            decode_clip(props, reg, p, c + 1, b4);
            float4 f = make_float4(b4[0], b4[1], b4[2], b4[3]);
            myb[ns] = f;
            bx[idx] = f;
        }
    }
    LDS_FENCE();

    // greedy NMS: sequential i, suppression mask in registers (bit ns = slot)
    unsigned int my_sup = 0u;
    for (int i = 0; i < M; ++i) {
        int owner = i & 63, slot = i >> 6;
        unsigned int os = __shfl(my_sup, owner);
        if ((os >> slot) & 1u) continue;       // wave-uniform
        float4 bi = bx[i];                     // broadcast LDS read
        float ai = (bi.z - bi.x + 1.0f) * (bi.w - bi.y + 1.0f);
        #pragma unroll
        for (int ns = 0; ns < 8; ++ns) {
            int j = lane + ns * 64;
            if (j < M && j > i) {
                float4 bj = myb[ns];
                float aj = (bj.z - bj.x + 1.0f) * (bj.w - bj.y + 1.0f);
                float ltx = fmaxf(bi.x, bj.x), lty = fmaxf(bi.y, bj.y);
                float rbx = fminf(bi.z, bj.z), rby = fminf(bi.w, bj.w);
                float iw = fmaxf(rbx - ltx + 1.0f, 0.0f);
                float ih = fmaxf(rby - lty + 1.0f, 0.0f);
                float inter = iw * ih;
                float iou = inter / (ai + aj - inter);
                if (iou > 0.5f) my_sup |= (1u << ns);
            }
        }
    }

    // ballot-compact survivors (descending order), re-key with ~flat
    int base = 0;
    #pragma unroll
    for (int ns = 0; ns < 8; ++ns) {
        if (ns * 64 >= M) break;               // uniform
        int j = lane + ns * 64;
        bool keep = (j < M) && !((my_sup >> ns) & 1u);
        unsigned long long mask = __ballot(keep);
        if (keep) {
            int pos = base + __popcll(mask & ((1ULL << lane) - 1ULL));
            unsigned long long key = keys[j];
            int p = (int)(~(unsigned int)key);
            unsigned int flat = (unsigned int)(c * NPROP + p);
            surv[c * CAP + pos] =
                (key & 0xFFFFFFFF00000000ULL) | (unsigned int)(~flat);
        }
        base += __popcll(mask);
    }
    if (lane == 0) scnt[c] = base;
}

// single block: radix-select threshold bucket, compact ~K>=100 candidates,
// wave-synchronous sort, emit top-100.
__global__ __launch_bounds__(256) void topk_kernel(const int* __restrict__ scnt,
                                                   const unsigned long long* __restrict__ surv,
                                                   const float* __restrict__ props,
                                                   const float* __restrict__ reg,
                                                   float* __restrict__ out) {
    __shared__ unsigned int hist[NB];
    __shared__ unsigned long long comp[1024];
    __shared__ int s_n[NFG];
    __shared__ int sB;
    __shared__ int compN;
    const int tid = threadIdx.x;

    for (int i = tid; i < NB; i += 256) hist[i] = 0u;
    if (tid < NFG) {
        int k = scnt[tid];
        s_n[tid] = (k > TOPC) ? TOPC : k;
    }
    if (tid == 0) compN = 0;
    __syncthreads();

    // histogram of score high bits
    for (int idx = tid; idx < NFG * TOPC; idx += 256) {
        int cc = idx / TOPC, i = idx - cc * TOPC;
        if (i < s_n[cc]) {
            unsigned long long key = surv[cc * CAP + i];
            int b = (int)(((unsigned int)(key >> 32)) >> 15) - BMIN;
            b = b < 0 ? 0 : (b >= NB ? NB - 1 : b);
            atomicAdd(&hist[b], 1u);
        }
    }
    __syncthreads();

    // wave 0: suffix-sum from top to find threshold bucket (cum >= 100)
    if (tid < 64) {
        int lane = tid;
        int running = 0, Bstar = 0;
        bool found = false;
        for (int chunk = NB - 64; chunk >= 0; chunk -= 64) {
            int b = chunk + 63 - lane;          // lane 0 = highest bucket
            int s = (int)hist[b];
            #pragma unroll
            for (int d = 1; d < 64; d <<= 1) {
                int o = __shfl_up(s, d);
                if (lane >= d) s += o;
            }
            int cum = running + s;
            unsigned long long m = __ballot(cum >= TOPC);
            if (m != 0ULL) {
                int l = (int)__ffsll((unsigned long long)m) - 1;
                Bstar = chunk + 63 - l;
                found = true;
                break;
            }
            running += __shfl(s, 63);
        }
        if (!found) Bstar = 0;
        if (lane == 0) sB = Bstar;
    }
    __syncthreads();
    int Bstar = sB;

    // compact candidates with bucket >= Bstar
    for (int idx = tid; idx < NFG * TOPC; idx += 256) {
        int cc = idx / TOPC, i = idx - cc * TOPC;
        if (i < s_n[cc]) {
            unsigned long long key = surv[cc * CAP + i];
            int b = (int)(((unsigned int)(key >> 32)) >> 15) - BMIN;
            b = b < 0 ? 0 : (b >= NB ? NB - 1 : b);
            if (b >= Bstar) {
                int pos = atomicAdd(&compN, 1);
                if (pos < 1024) comp[pos] = key;
            }
        }
    }
    __syncthreads();
    int K = compN;
    if (K > 1024) K = 1024;
    int P = 128;
    while (P < K) P <<= 1;
    for (int i = K + tid; i < P; i += 256) comp[i] = 0ULL;
    __syncthreads();

    // wave 0: wave-synchronous bitonic sort descending over comp[0..P)
    if (tid < 64) {
        for (int k = 2; k <= P; k <<= 1) {
            for (int j = k >> 1; j > 0; j >>= 1) {
                for (int i = tid; i < P; i += 64) {
                    int l = i ^ j;
                    if (l > i) {
                        unsigned long long A = comp[i], B = comp[l];
                        bool dir = ((i & k) == 0);
                        if ((A < B) == dir) { comp[i] = B; comp[l] = A; }
                    }
                }
                LDS_FENCE();
            }
        }
    }
    __syncthreads();

    if (tid < TOPC) {
        unsigned long long key = comp[tid];
        float score;
        int flat;
        if (key == 0ULL) {             // < 100 total survivors: not expected
            score = -1.0f;
            flat = tid;
        } else {
            score = __uint_as_float((unsigned int)(key >> 32));
            flat = (int)(~(unsigned int)key);
        }
        int cc = flat >> 11;           // NPROP = 2^11
        int p = flat & (NPROP - 1);
        float b4[4];
        decode_clip(props, reg, p, cc + 1, b4);
        out[tid * 4 + 0] = b4[0];
        out[tid * 4 + 1] = b4[1];
        out[tid * 4 + 2] = b4[2];
        out[tid * 4 + 3] = b4[3];
        out[400 + tid] = score;
        out[500 + tid] = (float)(cc + 1);
    }
}

extern "C" void kernel_launch(void* const* d_in, const int* in_sizes, int n_in,
                              void* d_out, int out_size, void* d_ws, size_t ws_size,
                              hipStream_t stream) {
    const float* logits = (const float*)d_in[0];
    const float* reg    = (const float*)d_in[1];
    const float* props  = (const float*)d_in[2];
    float* out = (float*)d_out;

    int* ccnt = (int*)d_ws;
    int* scnt = (int*)((char*)d_ws + 5120);
    unsigned long long* cand = (unsigned long long*)((char*)d_ws + 5440);
    unsigned long long* surv = (unsigned long long*)((char*)d_ws + 333120);

    hipMemsetAsync(d_ws, 0, 5120, stream);
    hipLaunchKernelGGL(softmax_scatter, dim3((NPROP * 64) / 256), dim3(256), 0, stream,
                       logits, ccnt, cand);
    hipLaunchKernelGGL(nms_kernel, dim3(NFG), dim3(64), 0, stream,
                       ccnt, cand, props, reg, scnt, surv);
    hipLaunchKernelGGL(topk_kernel, dim3(1), dim3(256), 0, stream,
                       scnt, surv, props, reg, out);
}